// Round 12
// baseline (150.604 us; speedup 1.0000x reference)
//
#include <hip/hip_runtime.h>
#include <math.h>
#include <stdint.h>

// [SQ, B, NP, HN] fp32, unscaled QK^T softmax attention.
// Round-12 = R11 (best verified: fattn 60.4us) + T4 counted-vmcnt pipeline:
// triple-buffered LDS (96KB dynamic, 1 block/CU), raw s_barrier with
// s_waitcnt vmcnt(4) — stage(p+1)'s DMA stays in flight across the barrier
// (never vmcnt(0) in the main loop). Everything else identical to R11.
#define SQ 2048
#define NBH 32           // B*NP heads
#define HN 64
#define BQ 128           // queries per block (4 q-waves x 32)
#define BK2 128          // keys per loop phase (2 tiles, one per wave-group)
#define NP2 (SQ/BK2)     // 16 phases
#define TOK 2048         // floats between consecutive tokens (B*NP*HN)
#define HSTRIDE (SQ*HN)  // halfs per head in the f16 scratch layouts

typedef _Float16 half2v __attribute__((ext_vector_type(2)));
typedef _Float16 half4v __attribute__((ext_vector_type(4)));
typedef _Float16 half8v __attribute__((ext_vector_type(8)));
typedef float f32x16 __attribute__((ext_vector_type(16)));

__device__ __forceinline__ void async16(const void* g, void* l) {
  __builtin_amdgcn_global_load_lds(
      (const __attribute__((address_space(1))) void*)g,
      (__attribute__((address_space(3))) void*)l, 16, 0, 0);
}

__device__ __forceinline__ float fexp2(float x) {
#if __has_builtin(__builtin_amdgcn_exp2f)
  return __builtin_amdgcn_exp2f(x);
#else
  return exp2f(x);
#endif
}

// cross-half (lane ^ 32) reduce via v_permlane32_swap.
__device__ __forceinline__ float xmax32(float x) {
#if __has_builtin(__builtin_amdgcn_permlane32_swap)
  auto r = __builtin_amdgcn_permlane32_swap(__float_as_int(x), __float_as_int(x),
                                            false, false);
  return fmaxf(__int_as_float(r[0]), __int_as_float(r[1]));
#else
  return fmaxf(x, __shfl_xor(x, 32, 64));
#endif
}
__device__ __forceinline__ float xadd32(float x) {
#if __has_builtin(__builtin_amdgcn_permlane32_swap)
  auto r = __builtin_amdgcn_permlane32_swap(__float_as_int(x), __float_as_int(x),
                                            false, false);
  return __int_as_float(r[0]) + __int_as_float(r[1]);
#else
  return x + __shfl_xor(x, 32, 64);
#endif
}

// ---- prep (one launch): K -> Kh f16 [head][key][dim] (16B chunks xor-swizzled
// by key&7 within the 128B row); V -> Vt f16 [head][dim][key] (4-key units
// xor-swizzled by dim&15 within each 64-key tile).  XCD-swizzled head mapping
// (head h produced on XCD h%8, same mapping fattn consumes).  (= R9/R11)
__global__ __launch_bounds__(256) void prep_kv(const float* __restrict__ K,
                                               const float* __restrict__ V,
                                               _Float16* __restrict__ Kh,
                                               _Float16* __restrict__ Vt) {
  __shared__ _Float16 vs[HN * 64];
  const int t = threadIdx.x;
  const int pflat = blockIdx.y * 32 + blockIdx.x;       // 0..1023
  const int head = (pflat & 7) + 8 * (pflat >> 8);      // 0..31
  const int ck = (pflat >> 3) & 31;                     // key chunk 0..31
  // K part
  {
    const int key = ck * 64 + (t >> 2);
    const int c0 = (t & 3) * 2;
    const float* src = K + (size_t)key * TOK + head * HN + c0 * 8;
    float4 a = *(const float4*)src;
    float4 b = *(const float4*)(src + 4);
    float4 c = *(const float4*)(src + 8);
    float4 d = *(const float4*)(src + 12);
    half8v h0, h1;
    h0[0]=(_Float16)a.x; h0[1]=(_Float16)a.y; h0[2]=(_Float16)a.z; h0[3]=(_Float16)a.w;
    h0[4]=(_Float16)b.x; h0[5]=(_Float16)b.y; h0[6]=(_Float16)b.z; h0[7]=(_Float16)b.w;
    h1[0]=(_Float16)c.x; h1[1]=(_Float16)c.y; h1[2]=(_Float16)c.z; h1[3]=(_Float16)c.w;
    h1[4]=(_Float16)d.x; h1[5]=(_Float16)d.y; h1[6]=(_Float16)d.z; h1[7]=(_Float16)d.w;
    _Float16* row = Kh + (size_t)head * HSTRIDE + (size_t)key * 64;
    *(half8v*)&row[((c0    ) ^ (key & 7)) * 8] = h0;
    *(half8v*)&row[((c0 + 1) ^ (key & 7)) * 8] = h1;
  }
  // V part
  {
    const int kt = ck * 64;
    const int kl = (t >> 3) * 2;
    const int db = (t & 7) * 8;
    const float* src = V + (size_t)(kt + kl) * TOK + head * HN + db;
    float4 a0 = *(const float4*)src;
    float4 a1 = *(const float4*)(src + 4);
    float4 b0 = *(const float4*)(src + TOK);
    float4 b1 = *(const float4*)(src + TOK + 4);
    const float av[8] = {a0.x,a0.y,a0.z,a0.w,a1.x,a1.y,a1.z,a1.w};
    const float bv[8] = {b0.x,b0.y,b0.z,b0.w,b1.x,b1.y,b1.z,b1.w};
    const int u = kl >> 2;
    #pragma unroll
    for (int j = 0; j < 8; ++j) {
      const int dim = db + j;
      const int pos = u ^ (dim & 15);
      half2v h; h[0] = (_Float16)av[j]; h[1] = (_Float16)bv[j];
      *(half2v*)&vs[dim * 64 + pos * 4 + (kl & 3)] = h;
    }
    __syncthreads();
    const int dim = t >> 2;
    const int q = (t & 3) ^ (dim & 3);
    const _Float16* srow = &vs[dim * 64 + q * 16];
    _Float16* drow = Vt + (size_t)head * HSTRIDE + (size_t)dim * SQ + kt + q * 16;
    *(half8v*)&drow[0] = *(const half8v*)&srow[0];
    *(half8v*)&drow[8] = *(const half8v*)&srow[8];
  }
}

// ---- main: flash attention, S^T = K.Q^T via mfma_32x32x16_f16.
// KEY-SPLIT: 8 waves/block (512 thr). Waves 0-3 own the phase's first 64-key
// tile, waves 4-7 the second; each keeps private (m,l,acc); LDS merge at end.
// TRIPLE-BUFFERED staging with counted vmcnt: each wave issues 4
// global_load_lds per stage; at the top of phase p it waits vmcnt(4)
// (stage(p) done, stage(p+1)'s 4 newest still in flight) then raw s_barrier.
// Safety: a buffer's readers finish their ds_reads before their last MFMA
// (compiler use-waits) which precedes the barrier; its next DMA is issued
// only after that barrier.
// XCD swizzle: head = (p&7)+8*(p>>7). C layout: col = lane&31,
// row = (reg&3)+8*(reg>>2)+4*(lane>>5). PV uses permuted k-order. Q
// pre-scaled by log2(e). Defer-rescale THR=8 (exact). Padded merge (33).
__global__ __launch_bounds__(512, 2)
void fattn_mfma(const float* __restrict__ Q, const _Float16* __restrict__ Kh,
                const _Float16* __restrict__ Vt, float* __restrict__ O) {
  extern __shared__ __align__(16) _Float16 smem[];  // 98304 B
  _Float16* kbf = smem;            // 3 bufs x 8192 halfs (48 KB)
  _Float16* vtf = smem + 24576;    // 3 bufs x 8192 halfs (48 KB)

  const int t = threadIdx.x;
  const int lane = t & 63;
  const int w = t >> 6;            // 0..7
  const int qw = w & 3;            // query-wave within block
  const int g = w >> 2;            // key-group: 0 -> tile0, 1 -> tile1
  const int h2 = lane >> 5;
  const int l31 = lane & 31;
  // XCD swizzle: p in 0..511; head on XCD head%8; qc = (p>>3)&15
  const int pflat = blockIdx.y * 16 + blockIdx.x;
  const int head = (pflat & 7) + 8 * (pflat >> 7);
  const int qc = (pflat >> 3) & 15;
  const int q0 = qc * BQ + qw * 32;
  const _Float16* Kp = Kh + (size_t)head * HSTRIDE;
  const _Float16* Vp = Vt + (size_t)head * HSTRIDE;
  const int tb = g * 4096;         // group's tile base (halfs) within a buffer

  // ---- Q B-fragments x log2(e), registers all kernel (uses waited before loop)
  half8v qf[4];
  {
    const float* qp = Q + (size_t)(q0 + l31) * TOK + head * HN + 8 * h2;
    const float s = 1.44269504088896f;
    #pragma unroll
    for (int ks = 0; ks < 4; ++ks) {
      float4 a = *(const float4*)(qp + 16 * ks);
      float4 b = *(const float4*)(qp + 16 * ks + 4);
      half8v f;
      f[0] = (_Float16)(s*a.x); f[1] = (_Float16)(s*a.y); f[2] = (_Float16)(s*a.z); f[3] = (_Float16)(s*a.w);
      f[4] = (_Float16)(s*b.x); f[5] = (_Float16)(s*b.y); f[6] = (_Float16)(s*b.z); f[7] = (_Float16)(s*b.w);
      qf[ks] = f;
    }
  }

  f32x16 acc0, acc1;   // O^T partial frags: dims 0..31, 32..63 (this group's keys)
  #pragma unroll
  for (int r = 0; r < 16; ++r) { acc0[r] = 0.f; acc1[r] = 0.f; }
  float m_i = -INFINITY, l_i = 0.f;

  // async stage of phase p into buffer buf (0..2); 4 loads per wave.
  auto stage = [&](int p, int buf) {
    const size_t kt = (size_t)p * BK2;
    #pragma unroll
    for (int i = 0; i < 2; ++i) {                 // K: 16 KB
      const int off = w * 512 + i * 4096;
      async16(Kp + kt * 64 + off + lane * 8, kbf + buf * 8192 + off);
    }
    #pragma unroll
    for (int tl = 0; tl < 2; ++tl) {              // V: 16 KB
      const int off = w * 512;
      const int eo = off + lane * 8;
      const int dim = eo >> 6, inner = eo & 63;
      async16(Vp + (size_t)dim * SQ + kt + tl * 64 + inner,
              vtf + buf * 8192 + tl * 4096 + off);
    }
  };

  stage(0, 0);
  stage(1, 1);
  int cur = 0, nxt = 2;
  #pragma unroll 1
  for (int p = 0; p < NP2; ++p) {
    // counted wait: stage(p)'s 4 loads done; stage(p+1)'s 4 stay in flight.
    if (p + 1 < NP2) {
      asm volatile("s_waitcnt vmcnt(4)" ::: "memory");
    } else {
      asm volatile("s_waitcnt vmcnt(0)" ::: "memory");
    }
    __builtin_amdgcn_s_barrier();
    __builtin_amdgcn_sched_barrier(0);
    if (p + 2 < NP2) stage(p + 2, nxt);   // DMA overlaps all compute below
    const _Float16* kb = kbf + cur * 8192 + tb;
    const _Float16* vb = vtf + cur * 8192 + tb;

    // ---- S^T = K . Q^T for this group's 64-key tile (2 chains) ----
    f32x16 c0, c1;
    #pragma unroll
    for (int r = 0; r < 16; ++r) { c0[r] = 0.f; c1[r] = 0.f; }
    __builtin_amdgcn_s_setprio(1);
    #pragma unroll
    for (int ks = 0; ks < 4; ++ks) {
      const int pos = ((h2 + 2 * ks) ^ (l31 & 7)) * 8;
      half8v a0v = *(const half8v*)&kb[l31 * 64 + pos];
      half8v a1v = *(const half8v*)&kb[(l31 + 32) * 64 + pos];
      c0 = __builtin_amdgcn_mfma_f32_32x32x16_f16(a0v, qf[ks], c0, 0, 0, 0);
      c1 = __builtin_amdgcn_mfma_f32_32x32x16_f16(a1v, qf[ks], c1, 0, 0, 0);
    }
    __builtin_amdgcn_s_setprio(0);

    // ---- online softmax over this group's 64 keys (log2 domain) ----
    float tv[16];
    #pragma unroll
    for (int r = 0; r < 16; ++r) tv[r] = fmaxf(c0[r], c1[r]);
    float ma = fmaxf(fmaxf(tv[0], tv[1]), tv[2]);
    float mb = fmaxf(fmaxf(tv[3], tv[4]), tv[5]);
    float mc = fmaxf(fmaxf(tv[6], tv[7]), tv[8]);
    float md = fmaxf(fmaxf(tv[9], tv[10]), tv[11]);
    ma = fmaxf(fmaxf(ma, tv[12]), tv[13]);
    mb = fmaxf(fmaxf(mb, tv[14]), tv[15]);
    float mx = xmax32(fmaxf(fmaxf(ma, mb), fmaxf(mc, md)));
    // T13 defer-rescale (EXACT): only touch m/l/acc when some lane's tile max
    // exceeds m+8; otherwise P = exp2(S - m_old) <= 2^8 fits f16 fine.
    if (!__all(mx <= m_i + 8.f)) {
      const float mnew = fmaxf(m_i, mx);
      const float alpha = fexp2(m_i - mnew);   // 0 on first phase
      l_i *= alpha;
      m_i = mnew;
      #pragma unroll
      for (int r = 0; r < 16; ++r) { acc0[r] *= alpha; acc1[r] *= alpha; }
    }
    float rs0 = 0.f, rs1 = 0.f;
    #pragma unroll
    for (int r = 0; r < 16; ++r) {
      float p0 = fexp2(c0[r] - m_i);
      float p1 = fexp2(c1[r] - m_i);
      c0[r] = p0; c1[r] = p1;
      rs0 += p0; rs1 += p1;
    }
    l_i += xadd32(rs0 + rs1);

    // ---- PV for this tile: O^T += V^T . P^T, permuted k-order ----
    __builtin_amdgcn_s_setprio(1);
    #pragma unroll
    for (int ks = 0; ks < 4; ++ks) {
      const int rb = 8 * (ks & 1);
      const f32x16& s = (ks < 2) ? c0 : c1;
      union { half8v v8; half2v v2[4]; } pu;
      #pragma unroll
      for (int tt = 0; tt < 4; ++tt) {
        auto pk = __builtin_amdgcn_cvt_pkrtz(s[rb + 2 * tt], s[rb + 2 * tt + 1]);
        pu.v2[tt] = *(half2v*)&pk;
      }
      #pragma unroll
      for (int mbd = 0; mbd < 2; ++mbd) {
        const int dim = l31 + 32 * mbd;
        const int sw = dim & 15;
        union { half8v v8; half4v v4[2]; } au;
        au.v4[0] = *(const half4v*)&vb[dim * 64 + ((4 * ks + h2)     ^ sw) * 4];
        au.v4[1] = *(const half4v*)&vb[dim * 64 + ((4 * ks + 2 + h2) ^ sw) * 4];
        if (mbd == 0)
          acc0 = __builtin_amdgcn_mfma_f32_32x32x16_f16(au.v8, pu.v8, acc0, 0, 0, 0);
        else
          acc1 = __builtin_amdgcn_mfma_f32_32x32x16_f16(au.v8, pu.v8, acc1, 0, 0, 0);
      }
    }
    __builtin_amdgcn_s_setprio(0);

    cur = (cur == 2) ? 0 : cur + 1;
    nxt = (nxt == 2) ? 0 : nxt + 1;
  }

  // ---- merge the two key-groups' partials via LDS, then write O ----
  // stride 33 (pad): bank = (slot + r) % 32 -> 2-way (free) vs 32-way at 32.
  __syncthreads();                       // full drain before smem reuse
  float* fb = (float*)smem;
  const int slot = qw * 64 + lane;       // 0..255
  if (g == 1) {
    #pragma unroll
    for (int r = 0; r < 16; ++r) {
      fb[slot * 33 + r]      = acc0[r];
      fb[slot * 33 + 16 + r] = acc1[r];
    }
    fb[8448 + slot] = m_i;               // 256*33 = 8448
    fb[8704 + slot] = l_i;
  }
  __syncthreads();
  if (g == 0) {
    const float m2 = fb[8448 + slot];
    const float l2 = fb[8704 + slot];
    const float ms = fmaxf(m_i, m2);
    const float a0 = fexp2(m_i - ms);
    const float a1 = fexp2(m2 - ms);
    const float invl = 1.f / (l_i * a0 + l2 * a1);
    float* orow = O + (size_t)(q0 + l31) * TOK + head * HN;
    #pragma unroll
    for (int r = 0; r < 16; ++r) {
      const int d = (r & 3) + 8 * (r >> 2) + 4 * h2;
      orow[d]      = (acc0[r] * a0 + fb[slot * 33 + r]      * a1) * invl;
      orow[d + 32] = (acc1[r] * a0 + fb[slot * 33 + 16 + r] * a1) * invl;
    }
  }
}

extern "C" void kernel_launch(void* const* d_in, const int* in_sizes, int n_in,
                              void* d_out, int out_size, void* d_ws, size_t ws_size,
                              hipStream_t stream) {
  const float* Q = (const float*)d_in[0];
  const float* K = (const float*)d_in[1];
  const float* V = (const float*)d_in[2];
  float* O = (float*)d_out;
  _Float16* Kh = (_Float16*)d_ws;                       // 8 MB
  _Float16* Vh = Kh + (size_t)NBH * HSTRIDE;            // 8 MB
  static bool attr_done = false;
  if (!attr_done) {
    hipFuncSetAttribute(reinterpret_cast<const void*>(fattn_mfma),
                        hipFuncAttributeMaxDynamicSharedMemorySize, 98304);
    attr_done = true;
  }
  prep_kv<<<dim3(32, 32), 256, 0, stream>>>(K, V, Kh, Vh);
  fattn_mfma<<<dim3(SQ / BQ, NBH), 512, 98304, stream>>>(Q, Kh, Vh, O);
}

// Round 13
// 139.353 us; speedup vs baseline: 1.0807x; 1.0807x over previous
//
#include <hip/hip_runtime.h>
#include <math.h>
#include <stdint.h>

// [SQ, B, NP, HN] fp32, unscaled QK^T softmax attention.
// Round-13 = exact revert to R11, the verified session optimum:
// fattn 60.4us / total 141.4us. (R12's counted-vmcnt tri-buffer cost 1
// block/CU and regressed 20%; 2 blocks/CU is the measured sweet spot.)
// Structure: prep_kv (f16 scratch, XCD-pinned per head) + key-split 8-wave
// fattn (64KB LDS dbuf, defer-rescale THR=8, setprio, max3 tree, x2-unrolled
// phases, padded LDS merge).
#define SQ 2048
#define NBH 32           // B*NP heads
#define HN 64
#define BQ 128           // queries per block (4 q-waves x 32)
#define BK2 128          // keys per loop phase (2 tiles, one per wave-group)
#define NP2 (SQ/BK2)     // 16 phases
#define TOK 2048         // floats between consecutive tokens (B*NP*HN)
#define HSTRIDE (SQ*HN)  // halfs per head in the f16 scratch layouts

typedef _Float16 half2v __attribute__((ext_vector_type(2)));
typedef _Float16 half4v __attribute__((ext_vector_type(4)));
typedef _Float16 half8v __attribute__((ext_vector_type(8)));
typedef float f32x16 __attribute__((ext_vector_type(16)));

__device__ __forceinline__ void async16(const void* g, void* l) {
  __builtin_amdgcn_global_load_lds(
      (const __attribute__((address_space(1))) void*)g,
      (__attribute__((address_space(3))) void*)l, 16, 0, 0);
}

__device__ __forceinline__ float fexp2(float x) {
#if __has_builtin(__builtin_amdgcn_exp2f)
  return __builtin_amdgcn_exp2f(x);
#else
  return exp2f(x);
#endif
}

// cross-half (lane ^ 32) reduce via v_permlane32_swap.
__device__ __forceinline__ float xmax32(float x) {
#if __has_builtin(__builtin_amdgcn_permlane32_swap)
  auto r = __builtin_amdgcn_permlane32_swap(__float_as_int(x), __float_as_int(x),
                                            false, false);
  return fmaxf(__int_as_float(r[0]), __int_as_float(r[1]));
#else
  return fmaxf(x, __shfl_xor(x, 32, 64));
#endif
}
__device__ __forceinline__ float xadd32(float x) {
#if __has_builtin(__builtin_amdgcn_permlane32_swap)
  auto r = __builtin_amdgcn_permlane32_swap(__float_as_int(x), __float_as_int(x),
                                            false, false);
  return __int_as_float(r[0]) + __int_as_float(r[1]);
#else
  return x + __shfl_xor(x, 32, 64);
#endif
}

// ---- prep (one launch): K -> Kh f16 [head][key][dim] (16B chunks xor-swizzled
// by key&7 within the 128B row); V -> Vt f16 [head][dim][key] (4-key units
// xor-swizzled by dim&15 within each 64-key tile).  XCD-swizzled head mapping
// (head h produced on XCD h%8, same mapping fattn consumes).
__global__ __launch_bounds__(256) void prep_kv(const float* __restrict__ K,
                                               const float* __restrict__ V,
                                               _Float16* __restrict__ Kh,
                                               _Float16* __restrict__ Vt) {
  __shared__ _Float16 vs[HN * 64];
  const int t = threadIdx.x;
  const int pflat = blockIdx.y * 32 + blockIdx.x;       // 0..1023
  const int head = (pflat & 7) + 8 * (pflat >> 8);      // 0..31
  const int ck = (pflat >> 3) & 31;                     // key chunk 0..31
  // K part
  {
    const int key = ck * 64 + (t >> 2);
    const int c0 = (t & 3) * 2;
    const float* src = K + (size_t)key * TOK + head * HN + c0 * 8;
    float4 a = *(const float4*)src;
    float4 b = *(const float4*)(src + 4);
    float4 c = *(const float4*)(src + 8);
    float4 d = *(const float4*)(src + 12);
    half8v h0, h1;
    h0[0]=(_Float16)a.x; h0[1]=(_Float16)a.y; h0[2]=(_Float16)a.z; h0[3]=(_Float16)a.w;
    h0[4]=(_Float16)b.x; h0[5]=(_Float16)b.y; h0[6]=(_Float16)b.z; h0[7]=(_Float16)b.w;
    h1[0]=(_Float16)c.x; h1[1]=(_Float16)c.y; h1[2]=(_Float16)c.z; h1[3]=(_Float16)c.w;
    h1[4]=(_Float16)d.x; h1[5]=(_Float16)d.y; h1[6]=(_Float16)d.z; h1[7]=(_Float16)d.w;
    _Float16* row = Kh + (size_t)head * HSTRIDE + (size_t)key * 64;
    *(half8v*)&row[((c0    ) ^ (key & 7)) * 8] = h0;
    *(half8v*)&row[((c0 + 1) ^ (key & 7)) * 8] = h1;
  }
  // V part
  {
    const int kt = ck * 64;
    const int kl = (t >> 3) * 2;
    const int db = (t & 7) * 8;
    const float* src = V + (size_t)(kt + kl) * TOK + head * HN + db;
    float4 a0 = *(const float4*)src;
    float4 a1 = *(const float4*)(src + 4);
    float4 b0 = *(const float4*)(src + TOK);
    float4 b1 = *(const float4*)(src + TOK + 4);
    const float av[8] = {a0.x,a0.y,a0.z,a0.w,a1.x,a1.y,a1.z,a1.w};
    const float bv[8] = {b0.x,b0.y,b0.z,b0.w,b1.x,b1.y,b1.z,b1.w};
    const int u = kl >> 2;
    #pragma unroll
    for (int j = 0; j < 8; ++j) {
      const int dim = db + j;
      const int pos = u ^ (dim & 15);
      half2v h; h[0] = (_Float16)av[j]; h[1] = (_Float16)bv[j];
      *(half2v*)&vs[dim * 64 + pos * 4 + (kl & 3)] = h;
    }
    __syncthreads();
    const int dim = t >> 2;
    const int q = (t & 3) ^ (dim & 3);
    const _Float16* srow = &vs[dim * 64 + q * 16];
    _Float16* drow = Vt + (size_t)head * HSTRIDE + (size_t)dim * SQ + kt + q * 16;
    *(half8v*)&drow[0] = *(const half8v*)&srow[0];
    *(half8v*)&drow[8] = *(const half8v*)&srow[8];
  }
}

// ---- main: flash attention, S^T = K.Q^T via mfma_32x32x16_f16.
// KEY-SPLIT: 8 waves/block (512 thr). Waves 0-3 own the phase's first 64-key
// tile, waves 4-7 the second; each keeps private (m,l,acc); LDS merge at end.
// XCD swizzle: head = (p&7)+8*(p>>7) -> a head's 16 blocks share one XCD L2.
// C layout: col = lane&31, row = (reg&3)+8*(reg>>2)+4*(lane>>5).
// PV uses permuted k-order pi(h2,j)=16ks+4h2+8*(j>>2)+(j&3) so P^T stays in regs.
// Q pre-scaled by log2(e) -> bare v_exp_f32. Defer-rescale THR=8 (exact).
__global__ __launch_bounds__(512, 4)
void fattn_mfma(const float* __restrict__ Q, const _Float16* __restrict__ Kh,
                const _Float16* __restrict__ Vt, float* __restrict__ O) {
  // flat 64 KB: K dbuf [2][128][64-swz] | V dbuf [2][2][64][64-swz]
  __shared__ __align__(16) _Float16 smem[4 * 8192];
  _Float16* kbf = smem;            // 2 bufs x 8192 halfs
  _Float16* vtf = smem + 16384;    // 2 bufs x 8192 halfs

  const int t = threadIdx.x;
  const int lane = t & 63;
  const int w = t >> 6;            // 0..7
  const int qw = w & 3;            // query-wave within block
  const int g = w >> 2;            // key-group: 0 -> tile0, 1 -> tile1
  const int h2 = lane >> 5;
  const int l31 = lane & 31;
  // XCD swizzle: p in 0..511; head on XCD head%8; qc = (p>>3)&15
  const int pflat = blockIdx.y * 16 + blockIdx.x;
  const int head = (pflat & 7) + 8 * (pflat >> 7);
  const int qc = (pflat >> 3) & 15;
  const int q0 = qc * BQ + qw * 32;
  const _Float16* Kp = Kh + (size_t)head * HSTRIDE;
  const _Float16* Vp = Vt + (size_t)head * HSTRIDE;
  const int tb = g * 4096;         // group's tile base (halfs) within a buffer

  // ---- Q B-fragments x log2(e), registers all kernel ----
  half8v qf[4];
  {
    const float* qp = Q + (size_t)(q0 + l31) * TOK + head * HN + 8 * h2;
    const float s = 1.44269504088896f;
    #pragma unroll
    for (int ks = 0; ks < 4; ++ks) {
      float4 a = *(const float4*)(qp + 16 * ks);
      float4 b = *(const float4*)(qp + 16 * ks + 4);
      half8v f;
      f[0] = (_Float16)(s*a.x); f[1] = (_Float16)(s*a.y); f[2] = (_Float16)(s*a.z); f[3] = (_Float16)(s*a.w);
      f[4] = (_Float16)(s*b.x); f[5] = (_Float16)(s*b.y); f[6] = (_Float16)(s*b.z); f[7] = (_Float16)(s*b.w);
      qf[ks] = f;
    }
  }

  f32x16 acc0, acc1;   // O^T partial frags: dims 0..31, 32..63 (this group's keys)
  #pragma unroll
  for (int r = 0; r < 16; ++r) { acc0[r] = 0.f; acc1[r] = 0.f; }
  float m_i = -INFINITY, l_i = 0.f;

  // async stage of phase p into buffer p&1; split across all 8 waves.
  auto stage = [&](int p) {
    const int buf = p & 1;
    const size_t kt = (size_t)p * BK2;
    #pragma unroll
    for (int i = 0; i < 2; ++i) {                 // K: 16 KB
      const int off = w * 512 + i * 4096;
      async16(Kp + kt * 64 + off + lane * 8, kbf + buf * 8192 + off);
    }
    #pragma unroll
    for (int tl = 0; tl < 2; ++tl) {              // V: 16 KB
      const int off = w * 512;
      const int eo = off + lane * 8;
      const int dim = eo >> 6, inner = eo & 63;
      async16(Vp + (size_t)dim * SQ + kt + tl * 64 + inner,
              vtf + buf * 8192 + tl * 4096 + off);
    }
  };

  // one 64-key phase; cur is a call-site literal (x2 unroll) so all LDS
  // addressing below is compile-time static per body.
  auto phase = [&](int p, int cur) {
    __syncthreads();                 // buf cur ready; prior readers of buf cur done
    if (p + 1 < NP2) stage(p + 1);   // overlaps all compute below
    const _Float16* kb = kbf + cur * 8192 + tb;
    const _Float16* vb = vtf + cur * 8192 + tb;

    // ---- S^T = K . Q^T for this group's 64-key tile (2 chains) ----
    f32x16 c0, c1;
    #pragma unroll
    for (int r = 0; r < 16; ++r) { c0[r] = 0.f; c1[r] = 0.f; }
    __builtin_amdgcn_s_setprio(1);
    #pragma unroll
    for (int ks = 0; ks < 4; ++ks) {
      const int pos = ((h2 + 2 * ks) ^ (l31 & 7)) * 8;
      half8v a0v = *(const half8v*)&kb[l31 * 64 + pos];
      half8v a1v = *(const half8v*)&kb[(l31 + 32) * 64 + pos];
      c0 = __builtin_amdgcn_mfma_f32_32x32x16_f16(a0v, qf[ks], c0, 0, 0, 0);
      c1 = __builtin_amdgcn_mfma_f32_32x32x16_f16(a1v, qf[ks], c1, 0, 0, 0);
    }
    __builtin_amdgcn_s_setprio(0);

    // ---- online softmax over this group's 64 keys (log2 domain) ----
    // pairwise max then v_max3-friendly tree (24 ops, 4-way ILP)
    float tv[16];
    #pragma unroll
    for (int r = 0; r < 16; ++r) tv[r] = fmaxf(c0[r], c1[r]);
    float ma = fmaxf(fmaxf(tv[0], tv[1]), tv[2]);
    float mb = fmaxf(fmaxf(tv[3], tv[4]), tv[5]);
    float mc = fmaxf(fmaxf(tv[6], tv[7]), tv[8]);
    float md = fmaxf(fmaxf(tv[9], tv[10]), tv[11]);
    ma = fmaxf(fmaxf(ma, tv[12]), tv[13]);
    mb = fmaxf(fmaxf(mb, tv[14]), tv[15]);
    float mx = xmax32(fmaxf(fmaxf(ma, mb), fmaxf(mc, md)));
    // T13 defer-rescale (EXACT): only touch m/l/acc when some lane's tile max
    // exceeds m+8; otherwise P = exp2(S - m_old) <= 2^8 fits f16 fine.
    if (!__all(mx <= m_i + 8.f)) {
      const float mnew = fmaxf(m_i, mx);
      const float alpha = fexp2(m_i - mnew);   // 0 on first phase
      l_i *= alpha;
      m_i = mnew;
      #pragma unroll
      for (int r = 0; r < 16; ++r) { acc0[r] *= alpha; acc1[r] *= alpha; }
    }
    float rs0 = 0.f, rs1 = 0.f;
    #pragma unroll
    for (int r = 0; r < 16; ++r) {
      float p0 = fexp2(c0[r] - m_i);
      float p1 = fexp2(c1[r] - m_i);
      c0[r] = p0; c1[r] = p1;
      rs0 += p0; rs1 += p1;
    }
    l_i += xadd32(rs0 + rs1);

    // ---- PV for this tile: O^T += V^T . P^T, permuted k-order ----
    __builtin_amdgcn_s_setprio(1);
    #pragma unroll
    for (int ks = 0; ks < 4; ++ks) {
      const int rb = 8 * (ks & 1);
      const f32x16& s = (ks < 2) ? c0 : c1;
      union { half8v v8; half2v v2[4]; } pu;
      #pragma unroll
      for (int tt = 0; tt < 4; ++tt) {
        auto pk = __builtin_amdgcn_cvt_pkrtz(s[rb + 2 * tt], s[rb + 2 * tt + 1]);
        pu.v2[tt] = *(half2v*)&pk;
      }
      #pragma unroll
      for (int mbd = 0; mbd < 2; ++mbd) {
        const int dim = l31 + 32 * mbd;
        const int sw = dim & 15;
        union { half8v v8; half4v v4[2]; } au;
        au.v4[0] = *(const half4v*)&vb[dim * 64 + ((4 * ks + h2)     ^ sw) * 4];
        au.v4[1] = *(const half4v*)&vb[dim * 64 + ((4 * ks + 2 + h2) ^ sw) * 4];
        if (mbd == 0)
          acc0 = __builtin_amdgcn_mfma_f32_32x32x16_f16(au.v8, pu.v8, acc0, 0, 0, 0);
        else
          acc1 = __builtin_amdgcn_mfma_f32_32x32x16_f16(au.v8, pu.v8, acc1, 0, 0, 0);
      }
    }
    __builtin_amdgcn_s_setprio(0);
  };

  stage(0);
  #pragma unroll 1
  for (int p = 0; p < NP2; p += 2) {   // x2 unroll: cur literal per body
    phase(p, 0);
    phase(p + 1, 1);
  }

  // ---- merge the two key-groups' partials via LDS, then write O ----
  // stride 33 (pad): bank = (slot + r) % 32 -> 2-way (free) vs 32-way at 32.
  __syncthreads();                       // all LDS reads of main loop done
  float* fb = (float*)smem;              // 16384 floats available
  const int slot = qw * 64 + lane;       // 0..255
  if (g == 1) {
    #pragma unroll
    for (int r = 0; r < 16; ++r) {
      fb[slot * 33 + r]      = acc0[r];
      fb[slot * 33 + 16 + r] = acc1[r];
    }
    fb[8448 + slot] = m_i;               // 256*33 = 8448
    fb[8704 + slot] = l_i;
  }
  __syncthreads();
  if (g == 0) {
    const float m2 = fb[8448 + slot];
    const float l2 = fb[8704 + slot];
    const float ms = fmaxf(m_i, m2);
    const float a0 = fexp2(m_i - ms);
    const float a1 = fexp2(m2 - ms);
    const float invl = 1.f / (l_i * a0 + l2 * a1);
    float* orow = O + (size_t)(q0 + l31) * TOK + head * HN;
    #pragma unroll
    for (int r = 0; r < 16; ++r) {
      const int d = (r & 3) + 8 * (r >> 2) + 4 * h2;
      orow[d]      = (acc0[r] * a0 + fb[slot * 33 + r]      * a1) * invl;
      orow[d + 32] = (acc1[r] * a0 + fb[slot * 33 + 16 + r] * a1) * invl;
    }
  }
}

extern "C" void kernel_launch(void* const* d_in, const int* in_sizes, int n_in,
                              void* d_out, int out_size, void* d_ws, size_t ws_size,
                              hipStream_t stream) {
  const float* Q = (const float*)d_in[0];
  const float* K = (const float*)d_in[1];
  const float* V = (const float*)d_in[2];
  float* O = (float*)d_out;
  _Float16* Kh = (_Float16*)d_ws;                       // 8 MB
  _Float16* Vh = Kh + (size_t)NBH * HSTRIDE;            // 8 MB
  prep_kv<<<dim3(32, 32), 256, 0, stream>>>(K, V, Kh, Vh);
  fattn_mfma<<<dim3(SQ / BQ, NBH), 512, 0, stream>>>(Q, Kh, Vh, O);
}